// Round 11
// baseline (178.172 us; speedup 1.0000x reference)
//
#include <hip/hip_runtime.h>

typedef short bf16x8 __attribute__((ext_vector_type(8)));
typedef float f32x4 __attribute__((ext_vector_type(4)));
typedef unsigned long long u64x2 __attribute__((ext_vector_type(2)));
typedef unsigned short u16;

// ---------- helpers ----------

__device__ __forceinline__ u16 f2b(float f) {
  unsigned int u = __float_as_uint(f);
  u += 0x7fffu + ((u >> 16) & 1u);   // RNE
  return (u16)(u >> 16);
}
__device__ __forceinline__ float b2f(u16 h) {
  return __uint_as_float((unsigned int)h << 16);
}

__device__ __forceinline__ void gload16(const void* g, void* l) {
  __builtin_amdgcn_global_load_lds(
      (const __attribute__((address_space(1))) void*)g,
      (__attribute__((address_space(3))) void*)l, 16, 0, 0);
}

#define SBAR() __builtin_amdgcn_sched_barrier(0)
#define BAR()  do { SBAR(); __builtin_amdgcn_s_barrier(); SBAR(); } while (0)
#define VM0()  do { asm volatile("s_waitcnt vmcnt(0)" ::: "memory"); SBAR(); } while (0)

// ---------- 128x128 BK=32 4-wave NT GEMM (r5/r8-proven) ----------
__device__ __forceinline__ void stage32(
    const u16* __restrict__ gA, int lda, const u16* __restrict__ gB, int ldb,
    u16* bufA, u16* bufB)
{
  const int t = threadIdx.x;
  const int r0 = t >> 2;
  const int cs = (((t & 3) ^ ((r0 >> 1) & 3)) * 8);
  char* da = (char*)bufA + t * 16;
  char* db = (char*)bufB + t * 16;
  gload16(gA + (size_t)r0 * lda + cs, da);
  gload16(gA + (size_t)(r0 + 64) * lda + cs, da + 4096);
  gload16(gB + (size_t)r0 * ldb + cs, db);
  gload16(gB + (size_t)(r0 + 64) * ldb + cs, db + 4096);
}

__device__ __forceinline__ void gemm128(
    const u16* __restrict__ A, int lda, const u16* __restrict__ B, int ldb,
    int i0, int j0, int nk, u16* lds, f32x4 acc[4][4])
{
  u16* bA0 = lds;
  u16* bB0 = lds + 4096;
  u16* bA1 = lds + 8192;
  u16* bB1 = lds + 12288;
  const int t = threadIdx.x, lane = t & 63, wid = t >> 6;
  const int wrow = wid >> 1, wcol = wid & 1;
  const int rr = lane & 15, kg = lane >> 4;
  const int off = ((kg ^ ((rr >> 1) & 3)) << 4);
  const u16* Ab = A + (size_t)i0 * lda;
  const u16* Bb = B + (size_t)j0 * ldb;

  stage32(Ab, lda, Bb, ldb, bA0, bB0);
  for (int kt = 0; kt < nk; ++kt) {
    if (kt + 1 < nk) {
      stage32(Ab + (size_t)(kt + 1) * 32, lda, Bb + (size_t)(kt + 1) * 32, ldb,
              (kt & 1) ? bA0 : bA1, (kt & 1) ? bB0 : bB1);
      asm volatile("s_waitcnt vmcnt(4)" ::: "memory");
    } else {
      asm volatile("s_waitcnt vmcnt(0)" ::: "memory");
    }
    BAR();
    const u16* cA = (kt & 1) ? bA1 : bA0;
    const u16* cB = (kt & 1) ? bB1 : bB0;
    bf16x8 af[4], bf[4];
#pragma unroll
    for (int mi = 0; mi < 4; ++mi)
      af[mi] = *(const bf16x8*)((const char*)cA + (wrow * 64 + mi * 16 + rr) * 64 + off);
#pragma unroll
    for (int ni = 0; ni < 4; ++ni)
      bf[ni] = *(const bf16x8*)((const char*)cB + (wcol * 64 + ni * 16 + rr) * 64 + off);
    __builtin_amdgcn_s_setprio(1);
#pragma unroll
    for (int mi = 0; mi < 4; ++mi)
#pragma unroll
      for (int ni = 0; ni < 4; ++ni)
        acc[mi][ni] = __builtin_amdgcn_mfma_f32_16x16x32_bf16(
            af[mi], bf[ni], acc[mi][ni], 0, 0, 0);
    __builtin_amdgcn_s_setprio(0);
    BAR();
  }
}

// ============ 256x256 8-wave NT GEMM, 8-phase / 4-slot ring (r7/r10) =======
__device__ __forceinline__ void stage_kt(const u16* g, int ld, u16* dst) {
  const int t = threadIdx.x;
#pragma unroll
  for (int r = 0; r < 2; ++r) {
    int idx = r * 512 + t;
    int row = idx >> 2, sl = idx & 3;
    gload16(g + (size_t)row * ld + ((sl ^ ((row >> 1) & 3)) << 3),
            (char*)dst + idx * 16);
  }
}

__device__ __forceinline__ void rd4(const u16* slot, int base, int kg, bf16x8 a[4]) {
  const int cs = ((kg ^ ((base >> 1) & 3)) << 3);
#pragma unroll
  for (int mi = 0; mi < 4; ++mi)
    a[mi] = *(const bf16x8*)(slot + (base + mi * 16) * 32 + cs);
}

__device__ __forceinline__ void mm16(const bf16x8 a[4], const bf16x8 b[4],
                                     f32x4 acc[8][4], int rh) {
  __builtin_amdgcn_s_setprio(1);
#pragma unroll
  for (int mi = 0; mi < 4; ++mi)
#pragma unroll
    for (int ni = 0; ni < 4; ++ni)
      acc[rh * 4 + mi][ni] = __builtin_amdgcn_mfma_f32_16x16x32_bf16(
          a[mi], b[ni], acc[rh * 4 + mi][ni], 0, 0, 0);
  __builtin_amdgcn_s_setprio(0);
}

__device__ __forceinline__ void ktbody(
    int kt, int L, const u16* As, int lda, const u16* Bs, int ldb,
    u16* lds, int aBase0, int aBase1, int bBase, int kg,
    bf16x8 aC0[4], bf16x8 bCur[4], bf16x8 bNxt[4], f32x4 acc[8][4])
{
  const u16* slot = lds + (kt & 3) * 16384;
  bf16x8 aC1[4];
  rd4(slot, aBase1, kg, aC1);
  if (kt + 3 <= L)
    stage_kt(As + (size_t)(kt + 3) * 32, lda, lds + ((kt + 3) & 3) * 16384);
  if (kt + 3 <= L)      { asm volatile("s_waitcnt vmcnt(6)" ::: "memory"); }
  else if (kt + 2 <= L) { asm volatile("s_waitcnt vmcnt(4)" ::: "memory"); }
  else                  { asm volatile("s_waitcnt vmcnt(0)" ::: "memory"); }
  SBAR();
  BAR();
  mm16(aC0, bCur, acc, 0);
  BAR();
  if (kt < L) {
    const u16* sn = lds + ((kt + 1) & 3) * 16384;
    rd4(sn, aBase0, kg, aC0);
    rd4(sn + 8192, bBase, kg, bNxt);
  }
  if (kt + 3 <= L)
    stage_kt(Bs + (size_t)(kt + 3) * 32, ldb,
             lds + ((kt + 3) & 3) * 16384 + 8192);
  BAR();
  mm16(aC1, bCur, acc, 1);
  BAR();
}

__device__ __forceinline__ void gemm256(
    const u16* __restrict__ A, int lda, const u16* __restrict__ B, int ldb,
    int i0, int j0, int nkt, u16* lds, f32x4 acc[8][4])
{
  const int t = threadIdx.x, lane = t & 63, wid = t >> 6;
  const int wr = wid >> 2, wc = wid & 3;
  const int rr = lane & 15, kg = lane >> 4;
  const u16* As = A + (size_t)i0 * lda;
  const u16* Bs = B + (size_t)j0 * ldb;
  const int aBase0 = wr * 128 + rr;
  const int aBase1 = wr * 128 + 64 + rr;
  const int bBase  = wc * 64 + rr;
  const int L = nkt - 1;

#pragma unroll
  for (int k = 0; k < 3; ++k) {
    u16* sl = lds + k * 16384;
    stage_kt(As + (size_t)k * 32, lda, sl);
    stage_kt(Bs + (size_t)k * 32, ldb, sl + 8192);
  }
  asm volatile("s_waitcnt vmcnt(8)" ::: "memory");
  SBAR();
  BAR();
  bf16x8 aC0[4], bA[4], bB[4];
  rd4(lds, aBase0, kg, aC0);
  rd4(lds + 8192, bBase, kg, bA);

  for (int kt = 0; kt < nkt; kt += 2) {
    ktbody(kt,     L, As, lda, Bs, ldb, lds, aBase0, aBase1, bBase, kg, aC0, bA, bB, acc);
    ktbody(kt + 1, L, As, lda, Bs, ldb, lds, aBase0, aBase1, bBase, kg, aC0, bB, bA, acc);
  }
  VM0();
  BAR();
}

// ---------- kernel 0: prep0 — W transposes, P/Wv convert, w vector ----------
// [0,256): WqT/WkpT tiles | [256,2304): P | [2304,3328): Wv | [3328,3392): w
__global__ __launch_bounds__(256) void k_prep0(
    const float* __restrict__ Wq, const float* __restrict__ Wk,
    const float* __restrict__ Wv, const float* __restrict__ P,
    const float* __restrict__ bq,
    u16* __restrict__ WqTb, u16* __restrict__ WkpTb, u16* __restrict__ Wvb,
    u16* __restrict__ Ptab, float* __restrict__ w)
{
  const int bx = blockIdx.x, t = threadIdx.x;
  if (bx < 256) {
    __shared__ float ldsf[64 * 65];
    int tt = bx;
    int a0 = (tt & 15) * 64, c0 = (tt >> 4) * 64;
#pragma unroll
    for (int q = 0; q < 16; ++q) {
      int idx = q * 256 + t, r = idx >> 6, cc = idx & 63;
      ldsf[r * 65 + cc] = Wq[(size_t)(c0 + r) * 1024 + a0 + cc];
    }
    __syncthreads();
#pragma unroll
    for (int q = 0; q < 16; ++q) {
      int idx = q * 256 + t, r = idx >> 6, cc = idx & 63;
      WqTb[(size_t)(a0 + r) * 1024 + c0 + cc] = f2b(ldsf[cc * 65 + r]);
    }
    __syncthreads();
#pragma unroll
    for (int q = 0; q < 16; ++q) {
      int idx = q * 256 + t, r = idx >> 6, cc = idx & 63;
      ldsf[r * 65 + cc] = Wk[(size_t)(c0 + r) * 1024 + a0 + cc];
    }
    __syncthreads();
#pragma unroll
    for (int q = 0; q < 16; ++q) {
      int idx = q * 256 + t, r = idx >> 6, cc = idx & 63;
      float v = ldsf[cc * 65 + r] + ((c0 + cc == a0 + r) ? 1.0f : 0.0f);
      WkpTb[(size_t)(a0 + r) * 1024 + c0 + cc] = f2b(v);
    }
  } else if (bx < 2304) {
    size_t base = (size_t)(bx - 256) * 1024 + t * 4;
    float4 v = *(const float4*)(P + base);
    u16* dst = Ptab + base;
    dst[0] = f2b(v.x); dst[1] = f2b(v.y); dst[2] = f2b(v.z); dst[3] = f2b(v.w);
  } else if (bx < 3328) {
    size_t base = (size_t)(bx - 2304) * 1024 + t * 4;
    float4 v = *(const float4*)(Wv + base);
    u16* dst = Wvb + base;
    dst[0] = f2b(v.x); dst[1] = f2b(v.y); dst[2] = f2b(v.z); dst[3] = f2b(v.w);
  } else {
    int h = bx - 3328;            // w_d += sum_c bq_c * Wk[c][d]
    int d0 = t * 4;
    float4 a = {0.f, 0.f, 0.f, 0.f};
    for (int c = h * 16; c < h * 16 + 16; ++c) {
      float bqc = bq[c];
      float4 wv = *(const float4*)(Wk + (size_t)c * 1024 + d0);
      a.x += bqc * wv.x; a.y += bqc * wv.y;
      a.z += bqc * wv.z; a.w += bqc * wv.w;
    }
    atomicAdd(&w[d0], a.x); atomicAdd(&w[d0 + 1], a.y);
    atomicAdd(&w[d0 + 2], a.z); atomicAdd(&w[d0 + 3], a.w);
  }
}

// ---------- kernel 1: main1 — M/G GEMMs overlapped with x->bf16 convert ----
// [0,64): M = WqT x WkpT^T | [64,192): G = P x WqT^T | [192,8384): x convert.
// The 8192 BW-bound convert blocks co-run with (and hide) the 192
// latency-bound GEMM blocks.
__global__ __launch_bounds__(256) void k_main1(
    const float* __restrict__ x, const u16* __restrict__ WqTb,
    const u16* __restrict__ WkpTb, const u16* __restrict__ Ptab,
    u16* __restrict__ xb, u16* __restrict__ Mb, u16* __restrict__ Gb)
{
  __shared__ __align__(16) u16 lds[16384];
  const int bx = blockIdx.x, t = threadIdx.x;
  if (bx < 192) {
    const u16 *A, *B;
    u16* outp;
    int i0, j0;
    if (bx < 64) { A = WqTb; B = WkpTb; outp = Mb; i0 = (bx & 7) * 128; j0 = (bx >> 3) * 128; }
    else { int u = bx - 64; A = Ptab; B = WqTb; outp = Gb; i0 = (u & 15) * 128; j0 = (u >> 4) * 128; }
    f32x4 acc[4][4];
#pragma unroll
    for (int a = 0; a < 4; ++a)
#pragma unroll
      for (int c = 0; c < 4; ++c) acc[a][c] = (f32x4){0.f, 0.f, 0.f, 0.f};
    gemm128(A, 1024, B, 1024, i0, j0, 32, lds, acc);
    const int lane = t & 63, wid = t >> 6;
    const int wrow = wid >> 1, wcol = wid & 1;
    const int rr = lane & 15, kg = lane >> 4;
#pragma unroll
    for (int mi = 0; mi < 4; ++mi)
#pragma unroll
      for (int ni = 0; ni < 4; ++ni)
#pragma unroll
        for (int r = 0; r < 4; ++r) {
          int m = i0 + wrow * 64 + mi * 16 + kg * 4 + r;
          int n = j0 + wcol * 64 + ni * 16 + rr;
          outp[(size_t)m * 1024 + n] = f2b(acc[mi][ni][r]);
        }
  } else {
    size_t base = (size_t)(bx - 192) * 1024 + t * 4;
    float4 v = *(const float4*)(x + base);
    u16* dst = xb + base;
    dst[0] = f2b(v.x); dst[1] = f2b(v.y); dst[2] = f2b(v.z); dst[3] = f2b(v.w);
  }
}

// ---------- kernel 2: K2 = x M^T + G (bj<4) and V^T (bj>=4); 256 blocks ----
// bj==0 blocks also compute e'[row] = (x_row.(w+bq) + bq.P_row)/32.
__global__ __launch_bounds__(512, 2) void k_kv(
    const u16* __restrict__ xb, const u16* __restrict__ Mb,
    const u16* __restrict__ Gb, const u16* __restrict__ Wvb,
    const u16* __restrict__ Ptab,
    const float* __restrict__ bv, const float* __restrict__ bq,
    const float* __restrict__ wvec,
    u16* __restrict__ K2b, u16* __restrict__ Vtb, float* __restrict__ ep)
{
  extern __shared__ __align__(16) u16 lds[];
  const int bx = blockIdx.x;
  const int bi = bx & 31, bj = bx >> 5;   // 32 M-tiles x 8 N-tiles
  const int i0 = bi * 256;
  const bool isK2 = (bj < 4);
  const int j0 = (isK2 ? bj : (bj - 4)) * 256;
  f32x4 acc[8][4];
#pragma unroll
  for (int a = 0; a < 8; ++a)
#pragma unroll
    for (int b = 0; b < 4; ++b) acc[a][b] = (f32x4){0.f, 0.f, 0.f, 0.f};

  gemm256(xb, 1024, isK2 ? Mb : Wvb, 1024, i0, j0, 32, lds, acc);

  const int t = threadIdx.x, lane = t & 63, wid = t >> 6;
  const int wrow = wid >> 2, wcol = wid & 3;
  const int rr = lane & 15, kg = lane >> 4;
  if (isK2) {
#pragma unroll
    for (int mi = 0; mi < 8; ++mi)
#pragma unroll
      for (int ni = 0; ni < 4; ++ni)
#pragma unroll
        for (int r = 0; r < 4; ++r) {
          int m = i0 + wrow * 128 + mi * 16 + kg * 4 + r;
          int n = j0 + wcol * 64 + ni * 16 + rr;
          int s = m & 2047;
          K2b[(size_t)m * 1024 + n] =
              f2b(acc[mi][ni][r] + b2f(Gb[(size_t)s * 1024 + n]));
        }
    if (bj == 0) {
      // LDS is free after gemm256's trailing barrier.
      float* lwq = (float*)lds;
      float* lbq = ((float*)lds) + 1024;
      for (int i = t; i < 1024; i += 512) {
        float b = bq[i];
        lwq[i] = wvec[i] + b;
        lbq[i] = b;
      }
      __syncthreads();
      const int r = t >> 1, seg = t & 1;
      const int row = i0 + r;
      const int s = row & 2047;
      float tot = 0.f;
      for (int d0 = seg * 512; d0 < seg * 512 + 512; d0 += 8) {
        bf16x8 xv = *(const bf16x8*)(xb + (size_t)row * 1024 + d0);
        bf16x8 pv = *(const bf16x8*)(Ptab + (size_t)s * 1024 + d0);
#pragma unroll
        for (int u = 0; u < 8; ++u)
          tot += b2f((u16)xv[u]) * lwq[d0 + u] + b2f((u16)pv[u]) * lbq[d0 + u];
      }
      tot += __shfl_xor(tot, 1, 64);
      if (seg == 0) ep[row] = tot * 0.03125f;
    }
  } else {
    // V: transpose through swizzled LDS (256x256), then coalesced 16B stores
    u16* lt = lds;
#pragma unroll
    for (int mi = 0; mi < 8; ++mi)
#pragma unroll
      for (int ni = 0; ni < 4; ++ni) {
        int cl = wcol * 64 + ni * 16 + rr;            // d_local 0..255
        float bvd = bv[j0 + cl];
#pragma unroll
        for (int r = 0; r < 4; ++r) {
          int rl = wrow * 128 + mi * 16 + kg * 4 + r; // s_local 0..255
          lt[cl * 256 + (rl ^ ((cl & 7) << 3))] = f2b(acc[mi][ni][r] + bvd);
        }
      }
    __syncthreads();
    int b = i0 >> 11, s0 = i0 & 2047;
#pragma unroll
    for (int rnd = 0; rnd < 16; ++rnd) {
      int c = rnd * 512 + t;                  // 8192 x 16B chunks
      int drow = c >> 5, c16 = c & 31;
      int src = drow * 256 + ((c16 * 8) ^ ((drow & 7) << 3));
      *(u64x2*)(&Vtb[((size_t)b * 1024 + j0 + drow) * 2048 + s0 + c16 * 8]) =
          *(const u64x2*)(&lt[src]);
    }
  }
}

// ---------- kernel 3: scores = exp(x.K2/32 + e') + rowsum, XCD-chunked -----
__global__ __launch_bounds__(256, 4) void k_scores(
    const u16* __restrict__ xb, const u16* __restrict__ K2b,
    const float* __restrict__ ep,
    u16* __restrict__ Pb, float* __restrict__ rowsum)
{
  __shared__ __align__(16) u16 lds[16384];
  const int bx0 = blockIdx.x;
  const int lid = (bx0 & 7) * 68 + (bx0 >> 3);   // 544 = 8 x 68, bijective
  const int b = lid / 136;
  const int tt = lid - b * 136;
  int bi = 0;
  while ((bi + 1) * (bi + 2) / 2 <= tt) ++bi;
  const int bj = tt - bi * (bi + 1) / 2;
  const int i0 = bi * 128, j0 = bj * 128;
  const u16* A = xb + (size_t)b * 2048 * 1024;
  const u16* B = K2b + (size_t)b * 2048 * 1024;

  f32x4 acc[4][4];
#pragma unroll
  for (int a = 0; a < 4; ++a)
#pragma unroll
    for (int c = 0; c < 4; ++c) acc[a][c] = (f32x4){0.f, 0.f, 0.f, 0.f};

  gemm128(A, 1024, B, 1024, i0, j0, 32, lds, acc);

  const int t = threadIdx.x, lane = t & 63, wid = t >> 6;
  const int wrow = wid >> 1, wcol = wid & 1;
  const int rr = lane & 15, kg = lane >> 4;
  float* lrs = (float*)lds;
  __syncthreads();
  if (t < 128) lrs[t] = 0.f;
  __syncthreads();
  float epn[4];
#pragma unroll
  for (int ni = 0; ni < 4; ++ni)
    epn[ni] = ep[((size_t)b << 11) + j0 + wcol * 64 + ni * 16 + rr];
  u16* Pbb = Pb + (size_t)b * 2048 * 2048;
  const bool diag = (bi == bj);
#pragma unroll
  for (int mi = 0; mi < 4; ++mi)
#pragma unroll
    for (int r = 0; r < 4; ++r) {
      int lm = wrow * 64 + mi * 16 + kg * 4 + r;
      int m = i0 + lm;
      float rs = 0.f;
#pragma unroll
      for (int ni = 0; ni < 4; ++ni) {
        int n = j0 + wcol * 64 + ni * 16 + rr;
        float e = __expf(acc[mi][ni][r] * 0.03125f + epn[ni]);
        if (diag && n > m) e = 0.f;
        Pbb[(size_t)m * 2048 + n] = f2b(e);
        rs += e;
      }
      rs += __shfl_xor(rs, 1, 16);
      rs += __shfl_xor(rs, 2, 16);
      rs += __shfl_xor(rs, 4, 16);
      rs += __shfl_xor(rs, 8, 16);
      if (rr == 0) atomicAdd(&lrs[lm], rs);
    }
  __syncthreads();
  if (t < 128) atomicAdd(&rowsum[((size_t)b << 11) + i0 + t], lrs[t]);
}

// ---------- kernel 4: out = (Pexp @ V) / rowsum, depth-paired mapping ------
__global__ __launch_bounds__(256, 4) void k_pv(
    const u16* __restrict__ Pb, const u16* __restrict__ Vtb,
    const float* __restrict__ rowsum, float* __restrict__ out)
{
  __shared__ __align__(16) u16 lds[16384];
  const int bx = blockIdx.x;
  const int bj = bx & 7;
  const int b = (bx >> 3) & 3;
  const int u = bx >> 5;
  const int bi = (u < 8) ? (15 - u) : (u - 8);
  const int i0 = bi * 128, j0 = bj * 128;
  const u16* A = Pb + (size_t)b * 2048 * 2048;
  const u16* B = Vtb + (size_t)b * 1024 * 2048;

  f32x4 acc[4][4];
#pragma unroll
  for (int a = 0; a < 4; ++a)
#pragma unroll
    for (int c = 0; c < 4; ++c) acc[a][c] = (f32x4){0.f, 0.f, 0.f, 0.f};

  gemm128(A, 2048, B, 2048, i0, j0, (bi + 1) * 4, lds, acc);

  const int t = threadIdx.x, lane = t & 63, wid = t >> 6;
  const int wrow = wid >> 1, wcol = wid & 1;
  const int rr = lane & 15, kg = lane >> 4;
  const float* rsb = rowsum + ((size_t)b << 11);
  float* ob = out + (size_t)b * 2048 * 1024;
#pragma unroll
  for (int mi = 0; mi < 4; ++mi)
#pragma unroll
    for (int r = 0; r < 4; ++r) {
      int m = i0 + wrow * 64 + mi * 16 + kg * 4 + r;
      float inv = 1.0f / rsb[m];
#pragma unroll
      for (int ni = 0; ni < 4; ++ni) {
        int n = j0 + wcol * 64 + ni * 16 + rr;
        ob[(size_t)m * 1024 + n] = acc[mi][ni][r] * inv;
      }
    }
}

// ---------- launch ----------
extern "C" void kernel_launch(void* const* d_in, const int* in_sizes, int n_in,
                              void* d_out, int out_size, void* d_ws, size_t ws_size,
                              hipStream_t stream) {
  const float* x  = (const float*)d_in[0];
  const float* Wq = (const float*)d_in[1];
  const float* bq = (const float*)d_in[2];
  const float* Wk = (const float*)d_in[3];
  const float* bk = (const float*)d_in[4];  (void)bk; // folded (softmax-invariant)
  const float* Wv = (const float*)d_in[5];
  const float* bv = (const float*)d_in[6];
  const float* P  = (const float*)d_in[7];
  float* out = (float*)d_out;

  char* w_ = (char*)d_ws;
  u16*   xb     = (u16*)(w_);                   // 16 MB
  u16*   Wvb    = (u16*)(w_ + (16ull << 20));   //  2 MB
  u16*   WqTb   = (u16*)(w_ + (18ull << 20));   //  2 MB
  u16*   WkpTb  = (u16*)(w_ + (20ull << 20));   //  2 MB
  u16*   Ptab   = (u16*)(w_ + (22ull << 20));   //  4 MB
  u16*   Mb     = (u16*)(w_ + (26ull << 20));   //  2 MB
  u16*   Gb     = (u16*)(w_ + (28ull << 20));   //  4 MB
  u16*   K2b    = (u16*)(w_ + (32ull << 20));   // 16 MB
  u16*   Vtb    = (u16*)(w_ + (48ull << 20));   // 16 MB
  u16*   Pb     = (u16*)(w_ + (64ull << 20));   // 32 MB
  float* wvec   = (float*)(w_ + (96ull << 20));             // 4 KB
  float* rowsum = (float*)(w_ + (96ull << 20) + 4096);      // 32 KB
  float* ep     = (float*)(w_ + (96ull << 20) + 65536);     // 32 KB

  const int LDSB = 131072;
  (void)hipFuncSetAttribute((const void*)k_kv,
        hipFuncAttributeMaxDynamicSharedMemorySize, LDSB);

  hipMemsetAsync(wvec, 0, 4096 + 32768, stream);  // zero w + rowsum
  hipLaunchKernelGGL(k_prep0, dim3(3392), dim3(256), 0, stream,
                     Wq, Wk, Wv, P, bq, WqTb, WkpTb, Wvb, Ptab, wvec);
  hipLaunchKernelGGL(k_main1, dim3(8384), dim3(256), 0, stream,
                     x, WqTb, WkpTb, Ptab, xb, Mb, Gb);
  hipLaunchKernelGGL(k_kv, dim3(256), dim3(512), LDSB, stream,
                     xb, Mb, Gb, Wvb, Ptab, bv, bq, wvec, K2b, Vtb, ep);
  hipLaunchKernelGGL(k_scores, dim3(544), dim3(256), 0, stream,
                     xb, K2b, ep, Pb, rowsum);
  hipLaunchKernelGGL(k_pv, dim3(512), dim3(256), 0, stream,
                     Pb, Vtb, rowsum, out);
}

// Round 12
// 150.743 us; speedup vs baseline: 1.1820x; 1.1820x over previous
//
#include <hip/hip_runtime.h>

typedef short bf16x8 __attribute__((ext_vector_type(8)));
typedef float f32x4 __attribute__((ext_vector_type(4)));
typedef unsigned long long u64x2 __attribute__((ext_vector_type(2)));
typedef unsigned short u16;

// ---------- helpers ----------

__device__ __forceinline__ u16 f2b(float f) {
  unsigned int u = __float_as_uint(f);
  u += 0x7fffu + ((u >> 16) & 1u);   // RNE
  return (u16)(u >> 16);
}
__device__ __forceinline__ float b2f(u16 h) {
  return __uint_as_float((unsigned int)h << 16);
}

__device__ __forceinline__ void gload16(const void* g, void* l) {
  __builtin_amdgcn_global_load_lds(
      (const __attribute__((address_space(1))) void*)g,
      (__attribute__((address_space(3))) void*)l, 16, 0, 0);
}

#define SBAR() __builtin_amdgcn_sched_barrier(0)
#define BAR()  do { SBAR(); __builtin_amdgcn_s_barrier(); SBAR(); } while (0)
#define VM0()  do { asm volatile("s_waitcnt vmcnt(0)" ::: "memory"); SBAR(); } while (0)

// ---------- 128x128 BK=32 4-wave NT GEMM (r5/r8-proven) ----------
__device__ __forceinline__ void stage32(
    const u16* __restrict__ gA, int lda, const u16* __restrict__ gB, int ldb,
    u16* bufA, u16* bufB)
{
  const int t = threadIdx.x;
  const int r0 = t >> 2;
  const int cs = (((t & 3) ^ ((r0 >> 1) & 3)) * 8);
  char* da = (char*)bufA + t * 16;
  char* db = (char*)bufB + t * 16;
  gload16(gA + (size_t)r0 * lda + cs, da);
  gload16(gA + (size_t)(r0 + 64) * lda + cs, da + 4096);
  gload16(gB + (size_t)r0 * ldb + cs, db);
  gload16(gB + (size_t)(r0 + 64) * ldb + cs, db + 4096);
}

__device__ __forceinline__ void gemm128(
    const u16* __restrict__ A, int lda, const u16* __restrict__ B, int ldb,
    int i0, int j0, int nk, u16* lds, f32x4 acc[4][4])
{
  u16* bA0 = lds;
  u16* bB0 = lds + 4096;
  u16* bA1 = lds + 8192;
  u16* bB1 = lds + 12288;
  const int t = threadIdx.x, lane = t & 63, wid = t >> 6;
  const int wrow = wid >> 1, wcol = wid & 1;
  const int rr = lane & 15, kg = lane >> 4;
  const int off = ((kg ^ ((rr >> 1) & 3)) << 4);
  const u16* Ab = A + (size_t)i0 * lda;
  const u16* Bb = B + (size_t)j0 * ldb;

  stage32(Ab, lda, Bb, ldb, bA0, bB0);
  for (int kt = 0; kt < nk; ++kt) {
    if (kt + 1 < nk) {
      stage32(Ab + (size_t)(kt + 1) * 32, lda, Bb + (size_t)(kt + 1) * 32, ldb,
              (kt & 1) ? bA0 : bA1, (kt & 1) ? bB0 : bB1);
      asm volatile("s_waitcnt vmcnt(4)" ::: "memory");
    } else {
      asm volatile("s_waitcnt vmcnt(0)" ::: "memory");
    }
    BAR();
    const u16* cA = (kt & 1) ? bA1 : bA0;
    const u16* cB = (kt & 1) ? bB1 : bB0;
    bf16x8 af[4], bf[4];
#pragma unroll
    for (int mi = 0; mi < 4; ++mi)
      af[mi] = *(const bf16x8*)((const char*)cA + (wrow * 64 + mi * 16 + rr) * 64 + off);
#pragma unroll
    for (int ni = 0; ni < 4; ++ni)
      bf[ni] = *(const bf16x8*)((const char*)cB + (wcol * 64 + ni * 16 + rr) * 64 + off);
    __builtin_amdgcn_s_setprio(1);
#pragma unroll
    for (int mi = 0; mi < 4; ++mi)
#pragma unroll
      for (int ni = 0; ni < 4; ++ni)
        acc[mi][ni] = __builtin_amdgcn_mfma_f32_16x16x32_bf16(
            af[mi], bf[ni], acc[mi][ni], 0, 0, 0);
    __builtin_amdgcn_s_setprio(0);
    BAR();
  }
}

// ============ 256x256 8-wave NT GEMM, 8-phase / 4-slot ring (r7/r10) =======
__device__ __forceinline__ void stage_kt(const u16* g, int ld, u16* dst) {
  const int t = threadIdx.x;
#pragma unroll
  for (int r = 0; r < 2; ++r) {
    int idx = r * 512 + t;
    int row = idx >> 2, sl = idx & 3;
    gload16(g + (size_t)row * ld + ((sl ^ ((row >> 1) & 3)) << 3),
            (char*)dst + idx * 16);
  }
}

__device__ __forceinline__ void rd4(const u16* slot, int base, int kg, bf16x8 a[4]) {
  const int cs = ((kg ^ ((base >> 1) & 3)) << 3);
#pragma unroll
  for (int mi = 0; mi < 4; ++mi)
    a[mi] = *(const bf16x8*)(slot + (base + mi * 16) * 32 + cs);
}

__device__ __forceinline__ void mm16(const bf16x8 a[4], const bf16x8 b[4],
                                     f32x4 acc[8][4], int rh) {
  __builtin_amdgcn_s_setprio(1);
#pragma unroll
  for (int mi = 0; mi < 4; ++mi)
#pragma unroll
    for (int ni = 0; ni < 4; ++ni)
      acc[rh * 4 + mi][ni] = __builtin_amdgcn_mfma_f32_16x16x32_bf16(
          a[mi], b[ni], acc[rh * 4 + mi][ni], 0, 0, 0);
  __builtin_amdgcn_s_setprio(0);
}

__device__ __forceinline__ void ktbody(
    int kt, int L, const u16* As, int lda, const u16* Bs, int ldb,
    u16* lds, int aBase0, int aBase1, int bBase, int kg,
    bf16x8 aC0[4], bf16x8 bCur[4], bf16x8 bNxt[4], f32x4 acc[8][4])
{
  const u16* slot = lds + (kt & 3) * 16384;
  bf16x8 aC1[4];
  rd4(slot, aBase1, kg, aC1);
  if (kt + 3 <= L)
    stage_kt(As + (size_t)(kt + 3) * 32, lda, lds + ((kt + 3) & 3) * 16384);
  if (kt + 3 <= L)      { asm volatile("s_waitcnt vmcnt(6)" ::: "memory"); }
  else if (kt + 2 <= L) { asm volatile("s_waitcnt vmcnt(4)" ::: "memory"); }
  else                  { asm volatile("s_waitcnt vmcnt(0)" ::: "memory"); }
  SBAR();
  BAR();
  mm16(aC0, bCur, acc, 0);
  BAR();
  if (kt < L) {
    const u16* sn = lds + ((kt + 1) & 3) * 16384;
    rd4(sn, aBase0, kg, aC0);
    rd4(sn + 8192, bBase, kg, bNxt);
  }
  if (kt + 3 <= L)
    stage_kt(Bs + (size_t)(kt + 3) * 32, ldb,
             lds + ((kt + 3) & 3) * 16384 + 8192);
  BAR();
  mm16(aC1, bCur, acc, 1);
  BAR();
}

__device__ __forceinline__ void gemm256(
    const u16* __restrict__ A, int lda, const u16* __restrict__ B, int ldb,
    int i0, int j0, int nkt, u16* lds, f32x4 acc[8][4])
{
  const int t = threadIdx.x, lane = t & 63, wid = t >> 6;
  const int wr = wid >> 2, wc = wid & 3;
  const int rr = lane & 15, kg = lane >> 4;
  const u16* As = A + (size_t)i0 * lda;
  const u16* Bs = B + (size_t)j0 * ldb;
  const int aBase0 = wr * 128 + rr;
  const int aBase1 = wr * 128 + 64 + rr;
  const int bBase  = wc * 64 + rr;
  const int L = nkt - 1;

#pragma unroll
  for (int k = 0; k < 3; ++k) {
    u16* sl = lds + k * 16384;
    stage_kt(As + (size_t)k * 32, lda, sl);
    stage_kt(Bs + (size_t)k * 32, ldb, sl + 8192);
  }
  asm volatile("s_waitcnt vmcnt(8)" ::: "memory");
  SBAR();
  BAR();
  bf16x8 aC0[4], bA[4], bB[4];
  rd4(lds, aBase0, kg, aC0);
  rd4(lds + 8192, bBase, kg, bA);

  for (int kt = 0; kt < nkt; kt += 2) {
    ktbody(kt,     L, As, lda, Bs, ldb, lds, aBase0, aBase1, bBase, kg, aC0, bA, bB, acc);
    ktbody(kt + 1, L, As, lda, Bs, ldb, lds, aBase0, aBase1, bBase, kg, aC0, bB, bA, acc);
  }
  VM0();
  BAR();
}

// ---------- kernel 0: prep0 — W transposes, P/Wv convert, w vector ----------
// [0,256): WqT/WkpT tiles | [256,2304): P | [2304,3328): Wv | [3328,3392): w
__global__ __launch_bounds__(256) void k_prep0(
    const float* __restrict__ Wq, const float* __restrict__ Wk,
    const float* __restrict__ Wv, const float* __restrict__ P,
    const float* __restrict__ bq,
    u16* __restrict__ WqTb, u16* __restrict__ WkpTb, u16* __restrict__ Wvb,
    u16* __restrict__ Ptab, float* __restrict__ w)
{
  const int bx = blockIdx.x, t = threadIdx.x;
  if (bx < 256) {
    __shared__ float ldsf[64 * 65];
    int tt = bx;
    int a0 = (tt & 15) * 64, c0 = (tt >> 4) * 64;
#pragma unroll
    for (int q = 0; q < 16; ++q) {
      int idx = q * 256 + t, r = idx >> 6, cc = idx & 63;
      ldsf[r * 65 + cc] = Wq[(size_t)(c0 + r) * 1024 + a0 + cc];
    }
    __syncthreads();
#pragma unroll
    for (int q = 0; q < 16; ++q) {
      int idx = q * 256 + t, r = idx >> 6, cc = idx & 63;
      WqTb[(size_t)(a0 + r) * 1024 + c0 + cc] = f2b(ldsf[cc * 65 + r]);
    }
    __syncthreads();
#pragma unroll
    for (int q = 0; q < 16; ++q) {
      int idx = q * 256 + t, r = idx >> 6, cc = idx & 63;
      ldsf[r * 65 + cc] = Wk[(size_t)(c0 + r) * 1024 + a0 + cc];
    }
    __syncthreads();
#pragma unroll
    for (int q = 0; q < 16; ++q) {
      int idx = q * 256 + t, r = idx >> 6, cc = idx & 63;
      float v = ldsf[cc * 65 + r] + ((c0 + cc == a0 + r) ? 1.0f : 0.0f);
      WkpTb[(size_t)(a0 + r) * 1024 + c0 + cc] = f2b(v);
    }
  } else if (bx < 2304) {
    size_t base = (size_t)(bx - 256) * 1024 + t * 4;
    float4 v = *(const float4*)(P + base);
    u16* dst = Ptab + base;
    dst[0] = f2b(v.x); dst[1] = f2b(v.y); dst[2] = f2b(v.z); dst[3] = f2b(v.w);
  } else if (bx < 3328) {
    size_t base = (size_t)(bx - 2304) * 1024 + t * 4;
    float4 v = *(const float4*)(Wv + base);
    u16* dst = Wvb + base;
    dst[0] = f2b(v.x); dst[1] = f2b(v.y); dst[2] = f2b(v.z); dst[3] = f2b(v.w);
  } else {
    int h = bx - 3328;            // w_d += sum_c bq_c * Wk[c][d]
    int d0 = t * 4;
    float4 a = {0.f, 0.f, 0.f, 0.f};
    for (int c = h * 16; c < h * 16 + 16; ++c) {
      float bqc = bq[c];
      float4 wv = *(const float4*)(Wk + (size_t)c * 1024 + d0);
      a.x += bqc * wv.x; a.y += bqc * wv.y;
      a.z += bqc * wv.z; a.w += bqc * wv.w;
    }
    atomicAdd(&w[d0], a.x); atomicAdd(&w[d0 + 1], a.y);
    atomicAdd(&w[d0 + 2], a.z); atomicAdd(&w[d0 + 3], a.w);
  }
}

// ---------- kernel 1: main1 — M/G GEMMs overlapped with x->bf16 convert ----
__global__ __launch_bounds__(256) void k_main1(
    const float* __restrict__ x, const u16* __restrict__ WqTb,
    const u16* __restrict__ WkpTb, const u16* __restrict__ Ptab,
    u16* __restrict__ xb, u16* __restrict__ Mb, u16* __restrict__ Gb)
{
  __shared__ __align__(16) u16 lds[16384];
  const int bx = blockIdx.x, t = threadIdx.x;
  if (bx < 192) {
    const u16 *A, *B;
    u16* outp;
    int i0, j0;
    if (bx < 64) { A = WqTb; B = WkpTb; outp = Mb; i0 = (bx & 7) * 128; j0 = (bx >> 3) * 128; }
    else { int u = bx - 64; A = Ptab; B = WqTb; outp = Gb; i0 = (u & 15) * 128; j0 = (u >> 4) * 128; }
    f32x4 acc[4][4];
#pragma unroll
    for (int a = 0; a < 4; ++a)
#pragma unroll
      for (int c = 0; c < 4; ++c) acc[a][c] = (f32x4){0.f, 0.f, 0.f, 0.f};
    gemm128(A, 1024, B, 1024, i0, j0, 32, lds, acc);
    const int lane = t & 63, wid = t >> 6;
    const int wrow = wid >> 1, wcol = wid & 1;
    const int rr = lane & 15, kg = lane >> 4;
#pragma unroll
    for (int mi = 0; mi < 4; ++mi)
#pragma unroll
      for (int ni = 0; ni < 4; ++ni)
#pragma unroll
        for (int r = 0; r < 4; ++r) {
          int m = i0 + wrow * 64 + mi * 16 + kg * 4 + r;
          int n = j0 + wcol * 64 + ni * 16 + rr;
          outp[(size_t)m * 1024 + n] = f2b(acc[mi][ni][r]);
        }
  } else {
    size_t base = (size_t)(bx - 192) * 1024 + t * 4;
    float4 v = *(const float4*)(x + base);
    u16* dst = xb + base;
    dst[0] = f2b(v.x); dst[1] = f2b(v.y); dst[2] = f2b(v.z); dst[3] = f2b(v.w);
  }
}

// ---------- kernel 1b: e'[row] = (x_row.(w+bq) + bq.P_row)/32 ----------
// 512 blocks x 4 rows (wave per row) — r10-proven inner code.
__global__ __launch_bounds__(256) void k_e(
    const u16* __restrict__ xb, const u16* __restrict__ Ptab,
    const float* __restrict__ bq, const float* __restrict__ w,
    float* __restrict__ ep)
{
  const int t = threadIdx.x;
  const int wid = t >> 6, lane = t & 63;
  const int row = blockIdx.x * 4 + wid;
  const int s = row & 2047;
  float tot = 0.f;
#pragma unroll
  for (int pass = 0; pass < 2; ++pass) {
    int d = pass * 512 + lane * 8;
    bf16x8 xv = *(const bf16x8*)(xb + (size_t)row * 1024 + d);
    bf16x8 pv = *(const bf16x8*)(Ptab + (size_t)s * 1024 + d);
    float4 w0 = *(const float4*)(w + d), w1 = *(const float4*)(w + d + 4);
    float4 q0 = *(const float4*)(bq + d), q1 = *(const float4*)(bq + d + 4);
    float wq[8] = {w0.x + q0.x, w0.y + q0.y, w0.z + q0.z, w0.w + q0.w,
                   w1.x + q1.x, w1.y + q1.y, w1.z + q1.z, w1.w + q1.w};
    float bv8[8] = {q0.x, q0.y, q0.z, q0.w, q1.x, q1.y, q1.z, q1.w};
#pragma unroll
    for (int u = 0; u < 8; ++u)
      tot += b2f((u16)xv[u]) * wq[u] + b2f((u16)pv[u]) * bv8[u];
  }
#pragma unroll
  for (int o = 32; o >= 1; o >>= 1) tot += __shfl_xor(tot, o, 64);
  if (lane == 0) ep[row] = tot * 0.03125f;
}

// ---------- kernel 2: K2 = x M^T + G (bj<4) and V^T (bj>=4); 256 blocks ----
// (r10 version, byte-for-byte — no epilogue grafts.)
__global__ __launch_bounds__(512, 2) void k_kv(
    const u16* __restrict__ xb, const u16* __restrict__ Mb,
    const u16* __restrict__ Gb, const u16* __restrict__ Wvb,
    const float* __restrict__ bv,
    u16* __restrict__ K2b, u16* __restrict__ Vtb)
{
  extern __shared__ __align__(16) u16 lds[];
  const int bx = blockIdx.x;
  const int bi = bx & 31, bj = bx >> 5;   // 32 M-tiles x 8 N-tiles
  const int i0 = bi * 256;
  const bool isK2 = (bj < 4);
  const int j0 = (isK2 ? bj : (bj - 4)) * 256;
  f32x4 acc[8][4];
#pragma unroll
  for (int a = 0; a < 8; ++a)
#pragma unroll
    for (int b = 0; b < 4; ++b) acc[a][b] = (f32x4){0.f, 0.f, 0.f, 0.f};

  gemm256(xb, 1024, isK2 ? Mb : Wvb, 1024, i0, j0, 32, lds, acc);

  const int t = threadIdx.x, lane = t & 63, wid = t >> 6;
  const int wrow = wid >> 2, wcol = wid & 3;
  const int rr = lane & 15, kg = lane >> 4;
  if (isK2) {
#pragma unroll
    for (int mi = 0; mi < 8; ++mi)
#pragma unroll
      for (int ni = 0; ni < 4; ++ni)
#pragma unroll
        for (int r = 0; r < 4; ++r) {
          int m = i0 + wrow * 128 + mi * 16 + kg * 4 + r;
          int n = j0 + wcol * 64 + ni * 16 + rr;
          int s = m & 2047;
          K2b[(size_t)m * 1024 + n] =
              f2b(acc[mi][ni][r] + b2f(Gb[(size_t)s * 1024 + n]));
        }
  } else {
    // V: transpose through swizzled LDS (256x256), then coalesced 16B stores
    u16* lt = lds;
#pragma unroll
    for (int mi = 0; mi < 8; ++mi)
#pragma unroll
      for (int ni = 0; ni < 4; ++ni) {
        int cl = wcol * 64 + ni * 16 + rr;            // d_local 0..255
        float bvd = bv[j0 + cl];
#pragma unroll
        for (int r = 0; r < 4; ++r) {
          int rl = wrow * 128 + mi * 16 + kg * 4 + r; // s_local 0..255
          lt[cl * 256 + (rl ^ ((cl & 7) << 3))] = f2b(acc[mi][ni][r] + bvd);
        }
      }
    __syncthreads();
    int b = i0 >> 11, s0 = i0 & 2047;
#pragma unroll
    for (int rnd = 0; rnd < 16; ++rnd) {
      int c = rnd * 512 + t;                  // 8192 x 16B chunks
      int drow = c >> 5, c16 = c & 31;
      int src = drow * 256 + ((c16 * 8) ^ ((drow & 7) << 3));
      *(u64x2*)(&Vtb[((size_t)b * 1024 + j0 + drow) * 2048 + s0 + c16 * 8]) =
          *(const u64x2*)(&lt[src]);
    }
  }
}

// ---------- kernel 3: scores = exp(x.K2/32 + e') + rowsum, XCD-chunked -----
__global__ __launch_bounds__(256, 4) void k_scores(
    const u16* __restrict__ xb, const u16* __restrict__ K2b,
    const float* __restrict__ ep,
    u16* __restrict__ Pb, float* __restrict__ rowsum)
{
  __shared__ __align__(16) u16 lds[16384];
  const int bx0 = blockIdx.x;
  const int lid = (bx0 & 7) * 68 + (bx0 >> 3);   // 544 = 8 x 68, bijective
  const int b = lid / 136;
  const int tt = lid - b * 136;
  int bi = 0;
  while ((bi + 1) * (bi + 2) / 2 <= tt) ++bi;
  const int bj = tt - bi * (bi + 1) / 2;
  const int i0 = bi * 128, j0 = bj * 128;
  const u16* A = xb + (size_t)b * 2048 * 1024;
  const u16* B = K2b + (size_t)b * 2048 * 1024;

  f32x4 acc[4][4];
#pragma unroll
  for (int a = 0; a < 4; ++a)
#pragma unroll
    for (int c = 0; c < 4; ++c) acc[a][c] = (f32x4){0.f, 0.f, 0.f, 0.f};

  gemm128(A, 1024, B, 1024, i0, j0, 32, lds, acc);

  const int t = threadIdx.x, lane = t & 63, wid = t >> 6;
  const int wrow = wid >> 1, wcol = wid & 1;
  const int rr = lane & 15, kg = lane >> 4;
  float* lrs = (float*)lds;
  __syncthreads();
  if (t < 128) lrs[t] = 0.f;
  __syncthreads();
  float epn[4];
#pragma unroll
  for (int ni = 0; ni < 4; ++ni)
    epn[ni] = ep[((size_t)b << 11) + j0 + wcol * 64 + ni * 16 + rr];
  u16* Pbb = Pb + (size_t)b * 2048 * 2048;
  const bool diag = (bi == bj);
#pragma unroll
  for (int mi = 0; mi < 4; ++mi)
#pragma unroll
    for (int r = 0; r < 4; ++r) {
      int lm = wrow * 64 + mi * 16 + kg * 4 + r;
      int m = i0 + lm;
      float rs = 0.f;
#pragma unroll
      for (int ni = 0; ni < 4; ++ni) {
        int n = j0 + wcol * 64 + ni * 16 + rr;
        float e = __expf(acc[mi][ni][r] * 0.03125f + epn[ni]);
        if (diag && n > m) e = 0.f;
        Pbb[(size_t)m * 2048 + n] = f2b(e);
        rs += e;
      }
      rs += __shfl_xor(rs, 1, 16);
      rs += __shfl_xor(rs, 2, 16);
      rs += __shfl_xor(rs, 4, 16);
      rs += __shfl_xor(rs, 8, 16);
      if (rr == 0) atomicAdd(&lrs[lm], rs);
    }
  __syncthreads();
  if (t < 128) atomicAdd(&rowsum[((size_t)b << 11) + i0 + t], lrs[t]);
}

// ---------- kernel 4: out = (Pexp @ V) / rowsum, depth-paired mapping ------
__global__ __launch_bounds__(256, 4) void k_pv(
    const u16* __restrict__ Pb, const u16* __restrict__ Vtb,
    const float* __restrict__ rowsum, float* __restrict__ out)
{
  __shared__ __align__(16) u16 lds[16384];
  const int bx = blockIdx.x;
  const int bj = bx & 7;
  const int b = (bx >> 3) & 3;
  const int u = bx >> 5;
  const int bi = (u < 8) ? (15 - u) : (u - 8);
  const int i0 = bi * 128, j0 = bj * 128;
  const u16* A = Pb + (size_t)b * 2048 * 2048;
  const u16* B = Vtb + (size_t)b * 1024 * 2048;

  f32x4 acc[4][4];
#pragma unroll
  for (int a = 0; a < 4; ++a)
#pragma unroll
    for (int c = 0; c < 4; ++c) acc[a][c] = (f32x4){0.f, 0.f, 0.f, 0.f};

  gemm128(A, 2048, B, 2048, i0, j0, (bi + 1) * 4, lds, acc);

  const int t = threadIdx.x, lane = t & 63, wid = t >> 6;
  const int wrow = wid >> 1, wcol = wid & 1;
  const int rr = lane & 15, kg = lane >> 4;
  const float* rsb = rowsum + ((size_t)b << 11);
  float* ob = out + (size_t)b * 2048 * 1024;
#pragma unroll
  for (int mi = 0; mi < 4; ++mi)
#pragma unroll
    for (int r = 0; r < 4; ++r) {
      int m = i0 + wrow * 64 + mi * 16 + kg * 4 + r;
      float inv = 1.0f / rsb[m];
#pragma unroll
      for (int ni = 0; ni < 4; ++ni) {
        int n = j0 + wcol * 64 + ni * 16 + rr;
        ob[(size_t)m * 1024 + n] = acc[mi][ni][r] * inv;
      }
    }
}

// ---------- launch ----------
extern "C" void kernel_launch(void* const* d_in, const int* in_sizes, int n_in,
                              void* d_out, int out_size, void* d_ws, size_t ws_size,
                              hipStream_t stream) {
  const float* x  = (const float*)d_in[0];
  const float* Wq = (const float*)d_in[1];
  const float* bq = (const float*)d_in[2];
  const float* Wk = (const float*)d_in[3];
  const float* bk = (const float*)d_in[4];  (void)bk; // folded (softmax-invariant)
  const float* Wv = (const float*)d_in[5];
  const float* bv = (const float*)d_in[6];
  const float* P  = (const float*)d_in[7];
  float* out = (float*)d_out;

  char* w_ = (char*)d_ws;
  u16*   xb     = (u16*)(w_);                   // 16 MB
  u16*   Wvb    = (u16*)(w_ + (16ull << 20));   //  2 MB
  u16*   WqTb   = (u16*)(w_ + (18ull << 20));   //  2 MB
  u16*   WkpTb  = (u16*)(w_ + (20ull << 20));   //  2 MB
  u16*   Ptab   = (u16*)(w_ + (22ull << 20));   //  4 MB
  u16*   Mb     = (u16*)(w_ + (26ull << 20));   //  2 MB
  u16*   Gb     = (u16*)(w_ + (28ull << 20));   //  4 MB
  u16*   K2b    = (u16*)(w_ + (32ull << 20));   // 16 MB
  u16*   Vtb    = (u16*)(w_ + (48ull << 20));   // 16 MB
  u16*   Pb     = (u16*)(w_ + (64ull << 20));   // 32 MB
  float* wvec   = (float*)(w_ + (96ull << 20));             // 4 KB
  float* rowsum = (float*)(w_ + (96ull << 20) + 4096);      // 32 KB
  float* ep     = (float*)(w_ + (96ull << 20) + 65536);     // 32 KB

  const int LDSB = 131072;
  (void)hipFuncSetAttribute((const void*)k_kv,
        hipFuncAttributeMaxDynamicSharedMemorySize, LDSB);

  hipMemsetAsync(wvec, 0, 4096 + 32768, stream);  // zero w + rowsum
  hipLaunchKernelGGL(k_prep0, dim3(3392), dim3(256), 0, stream,
                     Wq, Wk, Wv, P, bq, WqTb, WkpTb, Wvb, Ptab, wvec);
  hipLaunchKernelGGL(k_main1, dim3(8384), dim3(256), 0, stream,
                     x, WqTb, WkpTb, Ptab, xb, Mb, Gb);
  hipLaunchKernelGGL(k_e, dim3(2048), dim3(256), 0, stream,
                     xb, Ptab, bq, wvec, ep);
  hipLaunchKernelGGL(k_kv, dim3(256), dim3(512), LDSB, stream,
                     xb, Mb, Gb, Wvb, bv, K2b, Vtb);
  hipLaunchKernelGGL(k_scores, dim3(544), dim3(256), 0, stream,
                     xb, K2b, ep, Pb, rowsum);
  hipLaunchKernelGGL(k_pv, dim3(512), dim3(256), 0, stream,
                     Pb, Vtb, rowsum, out);
}

// Round 13
// 148.803 us; speedup vs baseline: 1.1974x; 1.0130x over previous
//
#include <hip/hip_runtime.h>

typedef short bf16x8 __attribute__((ext_vector_type(8)));
typedef float f32x4 __attribute__((ext_vector_type(4)));
typedef unsigned long long u64x2 __attribute__((ext_vector_type(2)));
typedef unsigned short u16;

// ---------- helpers ----------

__device__ __forceinline__ u16 f2b(float f) {
  unsigned int u = __float_as_uint(f);
  u += 0x7fffu + ((u >> 16) & 1u);   // RNE
  return (u16)(u >> 16);
}
__device__ __forceinline__ float b2f(u16 h) {
  return __uint_as_float((unsigned int)h << 16);
}

__device__ __forceinline__ void gload16(const void* g, void* l) {
  __builtin_amdgcn_global_load_lds(
      (const __attribute__((address_space(1))) void*)g,
      (__attribute__((address_space(3))) void*)l, 16, 0, 0);
}

#define SBAR() __builtin_amdgcn_sched_barrier(0)
#define BAR()  do { SBAR(); __builtin_amdgcn_s_barrier(); SBAR(); } while (0)
#define VM0()  do { asm volatile("s_waitcnt vmcnt(0)" ::: "memory"); SBAR(); } while (0)

// ---------- 128x128 BK=32 4-wave NT GEMM (r5/r8-proven) ----------
__device__ __forceinline__ void stage32(
    const u16* __restrict__ gA, int lda, const u16* __restrict__ gB, int ldb,
    u16* bufA, u16* bufB)
{
  const int t = threadIdx.x;
  const int r0 = t >> 2;
  const int cs = (((t & 3) ^ ((r0 >> 1) & 3)) * 8);
  char* da = (char*)bufA + t * 16;
  char* db = (char*)bufB + t * 16;
  gload16(gA + (size_t)r0 * lda + cs, da);
  gload16(gA + (size_t)(r0 + 64) * lda + cs, da + 4096);
  gload16(gB + (size_t)r0 * ldb + cs, db);
  gload16(gB + (size_t)(r0 + 64) * ldb + cs, db + 4096);
}

__device__ __forceinline__ void gemm128(
    const u16* __restrict__ A, int lda, const u16* __restrict__ B, int ldb,
    int i0, int j0, int nk, u16* lds, f32x4 acc[4][4])
{
  u16* bA0 = lds;
  u16* bB0 = lds + 4096;
  u16* bA1 = lds + 8192;
  u16* bB1 = lds + 12288;
  const int t = threadIdx.x, lane = t & 63, wid = t >> 6;
  const int wrow = wid >> 1, wcol = wid & 1;
  const int rr = lane & 15, kg = lane >> 4;
  const int off = ((kg ^ ((rr >> 1) & 3)) << 4);
  const u16* Ab = A + (size_t)i0 * lda;
  const u16* Bb = B + (size_t)j0 * ldb;

  stage32(Ab, lda, Bb, ldb, bA0, bB0);
  for (int kt = 0; kt < nk; ++kt) {
    if (kt + 1 < nk) {
      stage32(Ab + (size_t)(kt + 1) * 32, lda, Bb + (size_t)(kt + 1) * 32, ldb,
              (kt & 1) ? bA0 : bA1, (kt & 1) ? bB0 : bB1);
      asm volatile("s_waitcnt vmcnt(4)" ::: "memory");
    } else {
      asm volatile("s_waitcnt vmcnt(0)" ::: "memory");
    }
    BAR();
    const u16* cA = (kt & 1) ? bA1 : bA0;
    const u16* cB = (kt & 1) ? bB1 : bB0;
    bf16x8 af[4], bf[4];
#pragma unroll
    for (int mi = 0; mi < 4; ++mi)
      af[mi] = *(const bf16x8*)((const char*)cA + (wrow * 64 + mi * 16 + rr) * 64 + off);
#pragma unroll
    for (int ni = 0; ni < 4; ++ni)
      bf[ni] = *(const bf16x8*)((const char*)cB + (wcol * 64 + ni * 16 + rr) * 64 + off);
    __builtin_amdgcn_s_setprio(1);
#pragma unroll
    for (int mi = 0; mi < 4; ++mi)
#pragma unroll
      for (int ni = 0; ni < 4; ++ni)
        acc[mi][ni] = __builtin_amdgcn_mfma_f32_16x16x32_bf16(
            af[mi], bf[ni], acc[mi][ni], 0, 0, 0);
    __builtin_amdgcn_s_setprio(0);
    BAR();
  }
}

// ============ 256x256 8-wave NT GEMM, 8-phase / 4-slot ring (r7/r10) =======
__device__ __forceinline__ void stage_kt(const u16* g, int ld, u16* dst) {
  const int t = threadIdx.x;
#pragma unroll
  for (int r = 0; r < 2; ++r) {
    int idx = r * 512 + t;
    int row = idx >> 2, sl = idx & 3;
    gload16(g + (size_t)row * ld + ((sl ^ ((row >> 1) & 3)) << 3),
            (char*)dst + idx * 16);
  }
}

__device__ __forceinline__ void rd4(const u16* slot, int base, int kg, bf16x8 a[4]) {
  const int cs = ((kg ^ ((base >> 1) & 3)) << 3);
#pragma unroll
  for (int mi = 0; mi < 4; ++mi)
    a[mi] = *(const bf16x8*)(slot + (base + mi * 16) * 32 + cs);
}

__device__ __forceinline__ void mm16(const bf16x8 a[4], const bf16x8 b[4],
                                     f32x4 acc[8][4], int rh) {
  __builtin_amdgcn_s_setprio(1);
#pragma unroll
  for (int mi = 0; mi < 4; ++mi)
#pragma unroll
    for (int ni = 0; ni < 4; ++ni)
      acc[rh * 4 + mi][ni] = __builtin_amdgcn_mfma_f32_16x16x32_bf16(
          a[mi], b[ni], acc[rh * 4 + mi][ni], 0, 0, 0);
  __builtin_amdgcn_s_setprio(0);
}

__device__ __forceinline__ void ktbody(
    int kt, int L, const u16* As, int lda, const u16* Bs, int ldb,
    u16* lds, int aBase0, int aBase1, int bBase, int kg,
    bf16x8 aC0[4], bf16x8 bCur[4], bf16x8 bNxt[4], f32x4 acc[8][4])
{
  const u16* slot = lds + (kt & 3) * 16384;
  bf16x8 aC1[4];
  rd4(slot, aBase1, kg, aC1);
  if (kt + 3 <= L)
    stage_kt(As + (size_t)(kt + 3) * 32, lda, lds + ((kt + 3) & 3) * 16384);
  if (kt + 3 <= L)      { asm volatile("s_waitcnt vmcnt(6)" ::: "memory"); }
  else if (kt + 2 <= L) { asm volatile("s_waitcnt vmcnt(4)" ::: "memory"); }
  else                  { asm volatile("s_waitcnt vmcnt(0)" ::: "memory"); }
  SBAR();
  BAR();
  mm16(aC0, bCur, acc, 0);
  BAR();
  if (kt < L) {
    const u16* sn = lds + ((kt + 1) & 3) * 16384;
    rd4(sn, aBase0, kg, aC0);
    rd4(sn + 8192, bBase, kg, bNxt);
  }
  if (kt + 3 <= L)
    stage_kt(Bs + (size_t)(kt + 3) * 32, ldb,
             lds + ((kt + 3) & 3) * 16384 + 8192);
  BAR();
  mm16(aC1, bCur, acc, 1);
  BAR();
}

__device__ __forceinline__ void gemm256(
    const u16* __restrict__ A, int lda, const u16* __restrict__ B, int ldb,
    int i0, int j0, int nkt, u16* lds, f32x4 acc[8][4])
{
  const int t = threadIdx.x, lane = t & 63, wid = t >> 6;
  const int wr = wid >> 2, wc = wid & 3;
  const int rr = lane & 15, kg = lane >> 4;
  const u16* As = A + (size_t)i0 * lda;
  const u16* Bs = B + (size_t)j0 * ldb;
  const int aBase0 = wr * 128 + rr;
  const int aBase1 = wr * 128 + 64 + rr;
  const int bBase  = wc * 64 + rr;
  const int L = nkt - 1;

#pragma unroll
  for (int k = 0; k < 3; ++k) {
    u16* sl = lds + k * 16384;
    stage_kt(As + (size_t)k * 32, lda, sl);
    stage_kt(Bs + (size_t)k * 32, ldb, sl + 8192);
  }
  asm volatile("s_waitcnt vmcnt(8)" ::: "memory");
  SBAR();
  BAR();
  bf16x8 aC0[4], bA[4], bB[4];
  rd4(lds, aBase0, kg, aC0);
  rd4(lds + 8192, bBase, kg, bA);

  for (int kt = 0; kt < nkt; kt += 2) {
    ktbody(kt,     L, As, lda, Bs, ldb, lds, aBase0, aBase1, bBase, kg, aC0, bA, bB, acc);
    ktbody(kt + 1, L, As, lda, Bs, ldb, lds, aBase0, aBase1, bBase, kg, aC0, bB, bA, acc);
  }
  VM0();
  BAR();
}

// ---------- kernel 0: prep0 — W transposes, P/Wv convert, w vector ----------
// [0,256): WqT/WkpT tiles | [256,2304): P | [2304,3328): Wv | [3328,3392): w
__global__ __launch_bounds__(256) void k_prep0(
    const float* __restrict__ Wq, const float* __restrict__ Wk,
    const float* __restrict__ Wv, const float* __restrict__ P,
    const float* __restrict__ bq,
    u16* __restrict__ WqTb, u16* __restrict__ WkpTb, u16* __restrict__ Wvb,
    u16* __restrict__ Ptab, float* __restrict__ w)
{
  const int bx = blockIdx.x, t = threadIdx.x;
  if (bx < 256) {
    __shared__ float ldsf[64 * 65];
    int tt = bx;
    int a0 = (tt & 15) * 64, c0 = (tt >> 4) * 64;
#pragma unroll
    for (int q = 0; q < 16; ++q) {
      int idx = q * 256 + t, r = idx >> 6, cc = idx & 63;
      ldsf[r * 65 + cc] = Wq[(size_t)(c0 + r) * 1024 + a0 + cc];
    }
    __syncthreads();
#pragma unroll
    for (int q = 0; q < 16; ++q) {
      int idx = q * 256 + t, r = idx >> 6, cc = idx & 63;
      WqTb[(size_t)(a0 + r) * 1024 + c0 + cc] = f2b(ldsf[cc * 65 + r]);
    }
    __syncthreads();
#pragma unroll
    for (int q = 0; q < 16; ++q) {
      int idx = q * 256 + t, r = idx >> 6, cc = idx & 63;
      ldsf[r * 65 + cc] = Wk[(size_t)(c0 + r) * 1024 + a0 + cc];
    }
    __syncthreads();
#pragma unroll
    for (int q = 0; q < 16; ++q) {
      int idx = q * 256 + t, r = idx >> 6, cc = idx & 63;
      float v = ldsf[cc * 65 + r] + ((c0 + cc == a0 + r) ? 1.0f : 0.0f);
      WkpTb[(size_t)(a0 + r) * 1024 + c0 + cc] = f2b(v);
    }
  } else if (bx < 2304) {
    size_t base = (size_t)(bx - 256) * 1024 + t * 4;
    float4 v = *(const float4*)(P + base);
    u16* dst = Ptab + base;
    dst[0] = f2b(v.x); dst[1] = f2b(v.y); dst[2] = f2b(v.z); dst[3] = f2b(v.w);
  } else if (bx < 3328) {
    size_t base = (size_t)(bx - 2304) * 1024 + t * 4;
    float4 v = *(const float4*)(Wv + base);
    u16* dst = Wvb + base;
    dst[0] = f2b(v.x); dst[1] = f2b(v.y); dst[2] = f2b(v.z); dst[3] = f2b(v.w);
  } else {
    int h = bx - 3328;            // w_d += sum_c bq_c * Wk[c][d]
    int d0 = t * 4;
    float4 a = {0.f, 0.f, 0.f, 0.f};
    for (int c = h * 16; c < h * 16 + 16; ++c) {
      float bqc = bq[c];
      float4 wv = *(const float4*)(Wk + (size_t)c * 1024 + d0);
      a.x += bqc * wv.x; a.y += bqc * wv.y;
      a.z += bqc * wv.z; a.w += bqc * wv.w;
    }
    atomicAdd(&w[d0], a.x); atomicAdd(&w[d0 + 1], a.y);
    atomicAdd(&w[d0 + 2], a.z); atomicAdd(&w[d0 + 3], a.w);
  }
}

// ---------- kernel 1: main1 — M/G GEMMs ∥ x convert + e' fused ----------
// [0,64): M = WqT x WkpT^T | [64,192): G = P x WqT^T |
// [192,8384): x row convert + e'[row] = (x.(w+bq) + bq.P~row)/32 |
// [8384]: zero rowsum.
__global__ __launch_bounds__(256) void k_main1(
    const float* __restrict__ x, const u16* __restrict__ WqTb,
    const u16* __restrict__ WkpTb, const u16* __restrict__ Ptab,
    const float* __restrict__ bq, const float* __restrict__ wvec,
    u16* __restrict__ xb, u16* __restrict__ Mb, u16* __restrict__ Gb,
    float* __restrict__ ep, float* __restrict__ rowsum)
{
  __shared__ __align__(16) u16 lds[16384];
  const int bx = blockIdx.x, t = threadIdx.x;
  if (bx < 192) {
    const u16 *A, *B;
    u16* outp;
    int i0, j0;
    if (bx < 64) { A = WqTb; B = WkpTb; outp = Mb; i0 = (bx & 7) * 128; j0 = (bx >> 3) * 128; }
    else { int u = bx - 64; A = Ptab; B = WqTb; outp = Gb; i0 = (u & 15) * 128; j0 = (u >> 4) * 128; }
    f32x4 acc[4][4];
#pragma unroll
    for (int a = 0; a < 4; ++a)
#pragma unroll
      for (int c = 0; c < 4; ++c) acc[a][c] = (f32x4){0.f, 0.f, 0.f, 0.f};
    gemm128(A, 1024, B, 1024, i0, j0, 32, lds, acc);
    const int lane = t & 63, wid = t >> 6;
    const int wrow = wid >> 1, wcol = wid & 1;
    const int rr = lane & 15, kg = lane >> 4;
#pragma unroll
    for (int mi = 0; mi < 4; ++mi)
#pragma unroll
      for (int ni = 0; ni < 4; ++ni)
#pragma unroll
        for (int r = 0; r < 4; ++r) {
          int m = i0 + wrow * 64 + mi * 16 + kg * 4 + r;
          int n = j0 + wcol * 64 + ni * 16 + rr;
          outp[(size_t)m * 1024 + n] = f2b(acc[mi][ni][r]);
        }
  } else if (bx < 8384) {
    const int row = bx - 192;
    const int d0 = t * 4;
    size_t base = (size_t)row * 1024 + d0;
    float4 v = *(const float4*)(x + base);
    u16* dst = xb + base;
    dst[0] = f2b(v.x); dst[1] = f2b(v.y); dst[2] = f2b(v.z); dst[3] = f2b(v.w);
    // e' contribution (fp32 x):
    const int s = row & 2047;
    float4 wv = *(const float4*)(wvec + d0);
    float4 qv = *(const float4*)(bq + d0);
    const u16* pr = Ptab + (size_t)s * 1024 + d0;
    float loc = v.x * (wv.x + qv.x) + v.y * (wv.y + qv.y)
              + v.z * (wv.z + qv.z) + v.w * (wv.w + qv.w)
              + b2f(pr[0]) * qv.x + b2f(pr[1]) * qv.y
              + b2f(pr[2]) * qv.z + b2f(pr[3]) * qv.w;
#pragma unroll
    for (int o = 32; o >= 1; o >>= 1) loc += __shfl_xor(loc, o, 64);
    float* redf = (float*)lds;
    if ((t & 63) == 0) redf[t >> 6] = loc;
    __syncthreads();
    if (t == 0)
      ep[row] = (redf[0] + redf[1] + redf[2] + redf[3]) * 0.03125f;
  } else {
    float4 z = {0.f, 0.f, 0.f, 0.f};
    for (int i = t; i < 2048; i += 256) ((float4*)rowsum)[i] = z;
  }
}

// ---------- kernel 2: K2 = x M^T + G (bj<4), Vt = Wv x^T directly (bj>=4) --
// 256 blocks (1/CU). Vt branch: A=Wvb rows (d), B=xb rows (s) -> output is
// natively [d][global_s]; plain coalesced scalar stores, no LDS transpose.
__global__ __launch_bounds__(512, 2) void k_kv(
    const u16* __restrict__ xb, const u16* __restrict__ Mb,
    const u16* __restrict__ Gb, const u16* __restrict__ Wvb,
    const float* __restrict__ bv,
    u16* __restrict__ K2b, u16* __restrict__ Vtb)
{
  extern __shared__ __align__(16) u16 lds[];
  const int bx = blockIdx.x;
  const int bi = bx & 31, bj = bx >> 5;   // 32 tiles x 8 N-tiles
  const bool isK2 = (bj < 4);
  const int i0 = isK2 ? bi * 256 : (bj - 4) * 256;
  const int j0 = isK2 ? bj * 256 : bi * 256;
  f32x4 acc[8][4];
#pragma unroll
  for (int a = 0; a < 8; ++a)
#pragma unroll
    for (int b = 0; b < 4; ++b) acc[a][b] = (f32x4){0.f, 0.f, 0.f, 0.f};

  gemm256(isK2 ? xb : Wvb, 1024, isK2 ? Mb : xb, 1024, i0, j0, 32, lds, acc);

  const int t = threadIdx.x, lane = t & 63, wid = t >> 6;
  const int wrow = wid >> 2, wcol = wid & 3;
  const int rr = lane & 15, kg = lane >> 4;
  if (isK2) {
#pragma unroll
    for (int mi = 0; mi < 8; ++mi)
#pragma unroll
      for (int ni = 0; ni < 4; ++ni)
#pragma unroll
        for (int r = 0; r < 4; ++r) {
          int m = i0 + wrow * 128 + mi * 16 + kg * 4 + r;
          int n = j0 + wcol * 64 + ni * 16 + rr;
          int s = m & 2047;
          K2b[(size_t)m * 1024 + n] =
              f2b(acc[mi][ni][r] + b2f(Gb[(size_t)s * 1024 + n]));
        }
  } else {
#pragma unroll
    for (int mi = 0; mi < 8; ++mi)
#pragma unroll
      for (int r = 0; r < 4; ++r) {
        int m = i0 + wrow * 128 + mi * 16 + kg * 4 + r;   // d row
        float bvm = bv[m];
#pragma unroll
        for (int ni = 0; ni < 4; ++ni) {
          int n = j0 + wcol * 64 + ni * 16 + rr;          // global s
          int b = n >> 11, s = n & 2047;
          Vtb[((size_t)b * 1024 + m) * 2048 + s] = f2b(acc[mi][ni][r] + bvm);
        }
      }
  }
}

// ---------- kernel 3: scores = exp(x.K2/32 + e') + rowsum, XCD-chunked -----
__global__ __launch_bounds__(256, 4) void k_scores(
    const u16* __restrict__ xb, const u16* __restrict__ K2b,
    const float* __restrict__ ep,
    u16* __restrict__ Pb, float* __restrict__ rowsum)
{
  __shared__ __align__(16) u16 lds[16384];
  const int bx0 = blockIdx.x;
  const int lid = (bx0 & 7) * 68 + (bx0 >> 3);   // 544 = 8 x 68, bijective
  const int b = lid / 136;
  const int tt = lid - b * 136;
  int bi = 0;
  while ((bi + 1) * (bi + 2) / 2 <= tt) ++bi;
  const int bj = tt - bi * (bi + 1) / 2;
  const int i0 = bi * 128, j0 = bj * 128;
  const u16* A = xb + (size_t)b * 2048 * 1024;
  const u16* B = K2b + (size_t)b * 2048 * 1024;

  f32x4 acc[4][4];
#pragma unroll
  for (int a = 0; a < 4; ++a)
#pragma unroll
    for (int c = 0; c < 4; ++c) acc[a][c] = (f32x4){0.f, 0.f, 0.f, 0.f};

  gemm128(A, 1024, B, 1024, i0, j0, 32, lds, acc);

  const int t = threadIdx.x, lane = t & 63, wid = t >> 6;
  const int wrow = wid >> 1, wcol = wid & 1;
  const int rr = lane & 15, kg = lane >> 4;
  float* lrs = (float*)lds;
  __syncthreads();
  if (t < 128) lrs[t] = 0.f;
  __syncthreads();
  float epn[4];
#pragma unroll
  for (int ni = 0; ni < 4; ++ni)
    epn[ni] = ep[((size_t)b << 11) + j0 + wcol * 64 + ni * 16 + rr];
  u16* Pbb = Pb + (size_t)b * 2048 * 2048;
  const bool diag = (bi == bj);
#pragma unroll
  for (int mi = 0; mi < 4; ++mi)
#pragma unroll
    for (int r = 0; r < 4; ++r) {
      int lm = wrow * 64 + mi * 16 + kg * 4 + r;
      int m = i0 + lm;
      float rs = 0.f;
#pragma unroll
      for (int ni = 0; ni < 4; ++ni) {
        int n = j0 + wcol * 64 + ni * 16 + rr;
        float e = __expf(acc[mi][ni][r] * 0.03125f + epn[ni]);
        if (diag && n > m) e = 0.f;
        Pbb[(size_t)m * 2048 + n] = f2b(e);
        rs += e;
      }
      rs += __shfl_xor(rs, 1, 16);
      rs += __shfl_xor(rs, 2, 16);
      rs += __shfl_xor(rs, 4, 16);
      rs += __shfl_xor(rs, 8, 16);
      if (rr == 0) atomicAdd(&lrs[lm], rs);
    }
  __syncthreads();
  if (t < 128) atomicAdd(&rowsum[((size_t)b << 11) + i0 + t], lrs[t]);
}

// ---------- kernel 4: out = (Pexp @ V) / rowsum, depth-paired mapping ------
__global__ __launch_bounds__(256, 4) void k_pv(
    const u16* __restrict__ Pb, const u16* __restrict__ Vtb,
    const float* __restrict__ rowsum, float* __restrict__ out)
{
  __shared__ __align__(16) u16 lds[16384];
  const int bx = blockIdx.x;
  const int bj = bx & 7;
  const int b = (bx >> 3) & 3;
  const int u = bx >> 5;
  const int bi = (u < 8) ? (15 - u) : (u - 8);
  const int i0 = bi * 128, j0 = bj * 128;
  const u16* A = Pb + (size_t)b * 2048 * 2048;
  const u16* B = Vtb + (size_t)b * 1024 * 2048;

  f32x4 acc[4][4];
#pragma unroll
  for (int a = 0; a < 4; ++a)
#pragma unroll
    for (int c = 0; c < 4; ++c) acc[a][c] = (f32x4){0.f, 0.f, 0.f, 0.f};

  gemm128(A, 2048, B, 2048, i0, j0, (bi + 1) * 4, lds, acc);

  const int t = threadIdx.x, lane = t & 63, wid = t >> 6;
  const int wrow = wid >> 1, wcol = wid & 1;
  const int rr = lane & 15, kg = lane >> 4;
  const float* rsb = rowsum + ((size_t)b << 11);
  float* ob = out + (size_t)b * 2048 * 1024;
#pragma unroll
  for (int mi = 0; mi < 4; ++mi)
#pragma unroll
    for (int r = 0; r < 4; ++r) {
      int m = i0 + wrow * 64 + mi * 16 + kg * 4 + r;
      float inv = 1.0f / rsb[m];
#pragma unroll
      for (int ni = 0; ni < 4; ++ni) {
        int n = j0 + wcol * 64 + ni * 16 + rr;
        ob[(size_t)m * 1024 + n] = acc[mi][ni][r] * inv;
      }
    }
}

// ---------- launch ----------
extern "C" void kernel_launch(void* const* d_in, const int* in_sizes, int n_in,
                              void* d_out, int out_size, void* d_ws, size_t ws_size,
                              hipStream_t stream) {
  const float* x  = (const float*)d_in[0];
  const float* Wq = (const float*)d_in[1];
  const float* bq = (const float*)d_in[2];
  const float* Wk = (const float*)d_in[3];
  const float* bk = (const float*)d_in[4];  (void)bk; // folded (softmax-invariant)
  const float* Wv = (const float*)d_in[5];
  const float* bv = (const float*)d_in[6];
  const float* P  = (const float*)d_in[7];
  float* out = (float*)d_out;

  char* w_ = (char*)d_ws;
  u16*   xb     = (u16*)(w_);                   // 16 MB
  u16*   Wvb    = (u16*)(w_ + (16ull << 20));   //  2 MB
  u16*   WqTb   = (u16*)(w_ + (18ull << 20));   //  2 MB
  u16*   WkpTb  = (u16*)(w_ + (20ull << 20));   //  2 MB
  u16*   Ptab   = (u16*)(w_ + (22ull << 20));   //  4 MB
  u16*   Mb     = (u16*)(w_ + (26ull << 20));   //  2 MB
  u16*   Gb     = (u16*)(w_ + (28ull << 20));   //  4 MB
  u16*   K2b    = (u16*)(w_ + (32ull << 20));   // 16 MB
  u16*   Vtb    = (u16*)(w_ + (48ull << 20));   // 16 MB
  u16*   Pb     = (u16*)(w_ + (64ull << 20));   // 32 MB
  float* wvec   = (float*)(w_ + (96ull << 20));             // 4 KB
  float* rowsum = (float*)(w_ + (96ull << 20) + 4096);      // 32 KB
  float* ep     = (float*)(w_ + (96ull << 20) + 65536);     // 32 KB

  const int LDSB = 131072;
  (void)hipFuncSetAttribute((const void*)k_kv,
        hipFuncAttributeMaxDynamicSharedMemorySize, LDSB);

  hipMemsetAsync(wvec, 0, 4096, stream);  // zero w (rowsum zeroed in main1)
  hipLaunchKernelGGL(k_prep0, dim3(3392), dim3(256), 0, stream,
                     Wq, Wk, Wv, P, bq, WqTb, WkpTb, Wvb, Ptab, wvec);
  hipLaunchKernelGGL(k_main1, dim3(8385), dim3(256), 0, stream,
                     x, WqTb, WkpTb, Ptab, bq, wvec, xb, Mb, Gb, ep, rowsum);
  hipLaunchKernelGGL(k_kv, dim3(256), dim3(512), LDSB, stream,
                     xb, Mb, Gb, Wvb, bv, K2b, Vtb);
  hipLaunchKernelGGL(k_scores, dim3(544), dim3(256), 0, stream,
                     xb, K2b, ep, Pb, rowsum);
  hipLaunchKernelGGL(k_pv, dim3(512), dim3(256), 0, stream,
                     Pb, Vtb, rowsum, out);
}